// Round 4
// baseline (376.242 us; speedup 1.0000x reference)
//
#include <hip/hip_runtime.h>
#include <hip/hip_bf16.h>
#include <stdint.h>

typedef __bf16 bf16_t;
typedef __bf16 bf16x8 __attribute__((ext_vector_type(8)));
typedef float f32x4 __attribute__((ext_vector_type(4)));

#define BB 8
#define KK 1024
#define LL 1024
#define DD 1024
#define OO 6
#define EE 128
#define NN 768   // OO*EE

// ---------------------------------------------------------------------------
__device__ __forceinline__ void async_copy16(const void* gptr, void* lds) {
    __builtin_amdgcn_global_load_lds(
        (__attribute__((address_space(1))) void*)gptr,
        (__attribute__((address_space(3))) void*)lds,
        16, 0, 0);
}

__device__ __forceinline__ void split_bf16(float x, bf16_t& hi, bf16_t& lo) {
    hi = (bf16_t)x;
    lo = (bf16_t)(x - (float)hi);
}

// squash helper: given sp[12] (slot s = value index s*64+lane), produce vv[12].
__device__ __forceinline__ void squash_regs(const float* sp, float* vv, int lane) {
#pragma unroll
    for (int o = 0; o < 6; ++o) {
        float t = sp[2*o]*sp[2*o] + sp[2*o+1]*sp[2*o+1];
#pragma unroll
        for (int off = 32; off > 0; off >>= 1) t += __shfl_xor(t, off, 64);
        const float sc = t / (1.0f + t) / (sqrtf(t) + 1e-8f);
        vv[2*o]   = sc * sp[2*o];
        vv[2*o+1] = sc * sp[2*o+1];
    }
}

// ---------------------------------------------------------------------------
// A (8192,1024) f32 -> Ah, Al bf16 planes.
__global__ __launch_bounds__(256) void convert_a(
    const float* __restrict__ A, bf16_t* __restrict__ Ah, bf16_t* __restrict__ Al)
{
    const long i = ((long)blockIdx.x * 256 + threadIdx.x) * 4;
    const float4 x = *(const float4*)(A + i);
    union { bf16_t h[4]; uint2 u; } ph, pl;
    split_bf16(x.x, ph.h[0], pl.h[0]);
    split_bf16(x.y, ph.h[1], pl.h[1]);
    split_bf16(x.z, ph.h[2], pl.h[2]);
    split_bf16(x.w, ph.h[3], pl.h[3]);
    *(uint2*)(Ah + i) = ph.u;
    *(uint2*)(Al + i) = pl.u;
}

// ---------------------------------------------------------------------------
// W (O,D,E) f32 -> Wt_hi, Wt_lo (O,E,D) bf16 (transposed).
__global__ __launch_bounds__(256) void convert_w(
    const float* __restrict__ W, bf16_t* __restrict__ Wth, bf16_t* __restrict__ Wtl)
{
    __shared__ float t[32][33];
    const int o  = blockIdx.z;
    const int d0 = blockIdx.x * 32;
    const int e0 = blockIdx.y * 32;
    const int tx = threadIdx.x & 31;
    const int ty = threadIdx.x >> 5;
    const float* Wo = W + (long)o * DD * EE;
    bf16_t* Ho = Wth + (long)o * EE * DD;
    bf16_t* Lo = Wtl + (long)o * EE * DD;
#pragma unroll
    for (int p = 0; p < 4; ++p)
        t[p * 8 + ty][tx] = Wo[(long)(d0 + p * 8 + ty) * EE + e0 + tx];
    __syncthreads();
#pragma unroll
    for (int p = 0; p < 4; ++p) {
        const float val = t[tx][p * 8 + ty];
        bf16_t h, l;
        split_bf16(val, h, l);
        const long idx = (long)(e0 + p * 8 + ty) * DD + d0 + tx;
        Ho[idx] = h;
        Lo[idx] = l;
    }
}

// ---------------------------------------------------------------------------
// priors GEMM (split precision) + fused iter-0 s-accumulate epilogue.
// s0[b,col] += (1/6) * sum_k C[row,col] over this block's 128 rows.
__global__ __launch_bounds__(256) void gemm_priors(
    const bf16_t* __restrict__ Ah, const bf16_t* __restrict__ Al,
    const bf16_t* __restrict__ Bh, const bf16_t* __restrict__ Bl,
    float* __restrict__ C, float* __restrict__ s0)
{
    __shared__ alignas(16) bf16_t sAh[128 * 32];
    __shared__ alignas(16) bf16_t sAl[128 * 32];
    __shared__ alignas(16) bf16_t sBh[64 * 32];
    __shared__ alignas(16) bf16_t sBl[64 * 32];
    __shared__ float sRed[64];

    const int tid  = threadIdx.x;
    const int w    = tid >> 6;
    const int lane = tid & 63;
    const int bm   = blockIdx.x;   // 0..63
    const int bn   = blockIdx.y;   // 0..11
    const int qr   = (w >> 1) * 64;
    const int qc   = (w & 1) * 32;
    const int r16  = lane & 15;
    const int q    = lane >> 4;

    f32x4 acc[4][2] = {};

    const int mrowA = w * 32 + (lane >> 2);
    const int mrowB = w * 16 + (lane >> 2);
    const int kcol  = (lane & 3) * 8;

    const long aoff = (long)(bm * 128 + mrowA) * DD + kcol;
    const long boff = (long)(bn * 64  + mrowB) * DD + kcol;
    const bf16_t* gAh0 = Ah + aoff;  const bf16_t* gAh1 = gAh0 + 16 * DD;
    const bf16_t* gAl0 = Al + aoff;  const bf16_t* gAl1 = gAl0 + 16 * DD;
    const bf16_t* gBh  = Bh + boff;
    const bf16_t* gBl  = Bl + boff;

    bf16_t* lAh0 = sAh + (w * 2 + 0) * 512;
    bf16_t* lAh1 = sAh + (w * 2 + 1) * 512;
    bf16_t* lAl0 = sAl + (w * 2 + 0) * 512;
    bf16_t* lAl1 = sAl + (w * 2 + 1) * 512;
    bf16_t* lBh  = sBh + w * 512;
    bf16_t* lBl  = sBl + w * 512;

    for (int kt = 0; kt < DD / 32; ++kt) {
        const int k0 = kt * 32;
        async_copy16(gAh0 + k0, lAh0);
        async_copy16(gAh1 + k0, lAh1);
        async_copy16(gAl0 + k0, lAl0);
        async_copy16(gAl1 + k0, lAl1);
        async_copy16(gBh  + k0, lBh);
        async_copy16(gBl  + k0, lBl);
        __syncthreads();

        bf16x8 ah[4], al[4], bh[2], bl[2];
#pragma unroll
        for (int i = 0; i < 4; ++i) {
            const int ra = (qr + 16 * i + r16) * 32 + q * 8;
            ah[i] = *(const bf16x8*)(sAh + ra);
            al[i] = *(const bf16x8*)(sAl + ra);
        }
#pragma unroll
        for (int j = 0; j < 2; ++j) {
            const int rb = (qc + 16 * j + r16) * 32 + q * 8;
            bh[j] = *(const bf16x8*)(sBh + rb);
            bl[j] = *(const bf16x8*)(sBl + rb);
        }
#pragma unroll
        for (int i = 0; i < 4; ++i)
#pragma unroll
            for (int j = 0; j < 2; ++j) {
                acc[i][j] = __builtin_amdgcn_mfma_f32_16x16x32_bf16(
                    al[i], bh[j], acc[i][j], 0, 0, 0);
                acc[i][j] = __builtin_amdgcn_mfma_f32_16x16x32_bf16(
                    ah[i], bl[j], acc[i][j], 0, 0, 0);
                acc[i][j] = __builtin_amdgcn_mfma_f32_16x16x32_bf16(
                    ah[i], bh[j], acc[i][j], 0, 0, 0);
            }
        __syncthreads();
    }

    // C store. C/D layout: col = lane&15, row = (lane>>4)*4 + reg.
#pragma unroll
    for (int i = 0; i < 4; ++i)
#pragma unroll
        for (int j = 0; j < 2; ++j) {
            const int col = bn * 64 + qc + 16 * j + r16;
#pragma unroll
            for (int r = 0; r < 4; ++r) {
                const int row = bm * 128 + qr + 16 * i + q * 4 + r;
                C[(long)row * NN + col] = acc[i][j][r];
            }
        }

    // iter-0 s epilogue: column sums of this block's 128 rows.
    if (tid < 64) sRed[tid] = 0.f;
    __syncthreads();
#pragma unroll
    for (int j = 0; j < 2; ++j) {
        float cs = 0.f;
#pragma unroll
        for (int i = 0; i < 4; ++i)
            cs += acc[i][j][0] + acc[i][j][1] + acc[i][j][2] + acc[i][j][3];
        cs += __shfl_xor(cs, 16, 64);
        cs += __shfl_xor(cs, 32, 64);
        if (lane < 16)
            atomicAdd(&sRed[qc + 16 * j + r16], cs);
    }
    __syncthreads();
    if (tid < 64)
        atomicAdd(&s0[(bm >> 3) * NN + bn * 64 + tid], sRed[tid] * (1.0f / 6.0f));
}

// ---------------------------------------------------------------------------
// Fused routing step: v = squash(s_prev); per (b,k): delta = priors.v;
// g' = (first ? delta : g+delta); probs = mask ? 1/6 : softmax(g');
// s_cur += probs * priors (block-reduced + atomicAdd).
// grid 1024 blocks: b = blk>>7, 8 k per block; 4 waves x 2 rows.
__global__ __launch_bounds__(256) void pgs_kernel(
    const float* __restrict__ priors, const float* __restrict__ s_prev,
    const int* __restrict__ mask, float* __restrict__ g,
    float* __restrict__ probs, float* __restrict__ s_cur, int first)
{
    const int blk  = blockIdx.x;
    const int b    = blk >> 7;
    const int k8   = (blk & 127) * 8;
    const int w    = threadIdx.x >> 6;
    const int lane = threadIdx.x & 63;

    float vv[12];
    {
        float sp[12];
#pragma unroll
        for (int s = 0; s < 12; ++s) sp[s] = s_prev[b * NN + s * 64 + lane];
        squash_regs(sp, vv, lane);
    }

    float sacc[12];
#pragma unroll
    for (int s = 0; s < 12; ++s) sacc[s] = 0.f;

#pragma unroll
    for (int r = 0; r < 2; ++r) {
        const int k = k8 + w * 2 + r;
        const long rid = (long)b * KK + k;
        const float* pr = priors + rid * NN;
        float pp[12];
#pragma unroll
        for (int s = 0; s < 12; ++s) pp[s] = pr[s * 64 + lane];

        float d[6];
#pragma unroll
        for (int o = 0; o < 6; ++o) {
            float t = pp[2*o] * vv[2*o] + pp[2*o+1] * vv[2*o+1];
#pragma unroll
            for (int off = 32; off > 0; off >>= 1) t += __shfl_xor(t, off, 64);
            d[o] = t;
        }

        if (first) {
            if (lane < 6) {
                float x = d[0];
#pragma unroll
                for (int o = 1; o < 6; ++o) if (lane == o) x = d[o];
                g[rid * 6 + lane] = x;
            }
        } else {
#pragma unroll
            for (int o = 0; o < 6; ++o) d[o] += g[rid * 6 + o];
        }

        float p[6];
        if (mask[rid] != 0) {
#pragma unroll
            for (int o = 0; o < 6; ++o) p[o] = 1.0f / 6.0f;
        } else {
            float m = d[0];
#pragma unroll
            for (int o = 1; o < 6; ++o) m = fmaxf(m, d[o]);
            float ssum = 0.f;
#pragma unroll
            for (int o = 0; o < 6; ++o) { p[o] = expf(d[o] - m); ssum += p[o]; }
            const float inv = 1.0f / ssum;
#pragma unroll
            for (int o = 0; o < 6; ++o) p[o] *= inv;
        }

        if (!first && lane < 6) {
            float x = p[0];
#pragma unroll
            for (int o = 1; o < 6; ++o) if (lane == o) x = p[o];
            probs[rid * 6 + lane] = x;
        }

#pragma unroll
        for (int s = 0; s < 12; ++s) sacc[s] = fmaf(p[s >> 1], pp[s], sacc[s]);
    }

    __shared__ float red[4][768];
#pragma unroll
    for (int s = 0; s < 12; ++s) red[w][s * 64 + lane] = sacc[s];
    __syncthreads();
    const int t = threadIdx.x;
#pragma unroll
    for (int i = 0; i < 3; ++i) {
        const int flat = t + i * 256;
        atomicAdd(&s_cur[b * NN + flat],
                  red[0][flat] + red[1][flat] + red[2][flat] + red[3][flat]);
    }
}

// ---------------------------------------------------------------------------
// Output: V-section (squash(s2) broadcast over L) + P-section (probs bcast).
__global__ __launch_bounds__(256) void bcast_kernel(
    const float* __restrict__ s2, const float* __restrict__ P,
    float* __restrict__ out)
{
    const int blk = blockIdx.x;
    if (blk < 2048) {
        // V: b = blk>>8, 4 l-rows starting (blk&255)*4
        const int b  = blk >> 8;
        const int l0 = (blk & 255) * 4;
        const int w = threadIdx.x >> 6, lane = threadIdx.x & 63;
        __shared__ float vrow[768];
        if (w == 0) {
            float sp[12], vv[12];
#pragma unroll
            for (int s = 0; s < 12; ++s) sp[s] = s2[b * NN + s * 64 + lane];
            squash_regs(sp, vv, lane);
#pragma unroll
            for (int s = 0; s < 12; ++s) vrow[s * 64 + lane] = vv[s];
        }
        __syncthreads();
        float* dst = out + ((long)b * LL + l0) * NN;
        const int t = threadIdx.x;
#pragma unroll
        for (int i = 0; i < 3; ++i) {
            const int idx = t * 12 + i * 4;     // [0,3072)
            *(float4*)(dst + idx) = *(const float4*)(vrow + (idx % NN));
        }
    } else {
        const long NVF = (long)BB * LL * OO * EE;   // 6,291,456
        const int blk2 = blk - 2048;
        const long base = (long)blk2 * 4096;        // within P-section
        const int b = (int)(base / ((long)LL * KK * OO));
        const int choff = (int)(base % (KK * OO));
        const float* src = P + (long)b * (KK * OO);
        float* dst = out + NVF + base;
        const int t = threadIdx.x;
#pragma unroll
        for (int i = 0; i < 4; ++i) {
            int off = choff + t * 16 + i * 4;
            if (off >= KK * OO) off -= KK * OO;
            *(float4*)(dst + t * 16 + i * 4) = *(const float4*)(src + off);
        }
    }
}

// ---------------------------------------------------------------------------
extern "C" void kernel_launch(void* const* d_in, const int* in_sizes, int n_in,
                              void* d_out, int out_size, void* d_ws, size_t ws_size,
                              hipStream_t stream)
{
    (void)in_sizes; (void)n_in; (void)out_size; (void)ws_size;
    const float* u    = (const float*)d_in[0];
    const float* W    = (const float*)d_in[2];
    const int*   mask = (const int*)d_in[3];
    float*       out  = (float*)d_out;

    char* ws = (char*)d_ws;
    size_t off = 0;
    float*  priors = (float*)(ws + off);  off += (size_t)8192 * NN * 4;
    bf16_t* Ah     = (bf16_t*)(ws + off); off += (size_t)8192 * DD * 2;
    bf16_t* Al     = (bf16_t*)(ws + off); off += (size_t)8192 * DD * 2;
    bf16_t* Wth    = (bf16_t*)(ws + off); off += (size_t)OO * EE * DD * 2;
    bf16_t* Wtl    = (bf16_t*)(ws + off); off += (size_t)OO * EE * DD * 2;
    float*  g      = (float*)(ws + off);  off += (size_t)BB * KK * OO * 4;
    float*  probs  = (float*)(ws + off);  off += (size_t)BB * KK * OO * 4;
    float*  sbuf   = (float*)(ws + off);  off += (size_t)3 * BB * NN * 4;  // s0|s1|s2
    float*  s0 = sbuf, *s1 = sbuf + BB * NN, *s2 = sbuf + 2 * BB * NN;

    hipMemsetAsync(sbuf, 0, 3 * BB * NN * sizeof(float), stream);
    hipLaunchKernelGGL(convert_a, dim3(8192), dim3(256), 0, stream, u, Ah, Al);
    hipLaunchKernelGGL(convert_w, dim3(32, 4, 6), dim3(256), 0, stream, W, Wth, Wtl);
    hipLaunchKernelGGL(gemm_priors, dim3(64, 12), dim3(256), 0, stream,
                       Ah, Al, Wth, Wtl, priors, s0);
    hipLaunchKernelGGL(pgs_kernel, dim3(1024), dim3(256), 0, stream,
                       priors, s0, mask, g, probs, s1, 1);
    hipLaunchKernelGGL(pgs_kernel, dim3(1024), dim3(256), 0, stream,
                       priors, s1, mask, g, probs, s2, 0);
    hipLaunchKernelGGL(bcast_kernel, dim3(14336), dim3(256), 0, stream,
                       s2, probs, out);
}

// Round 5
// 373.748 us; speedup vs baseline: 1.0067x; 1.0067x over previous
//
#include <hip/hip_runtime.h>
#include <hip/hip_bf16.h>
#include <stdint.h>

typedef __bf16 bf16_t;
typedef __bf16 bf16x8 __attribute__((ext_vector_type(8)));
typedef float f32x4 __attribute__((ext_vector_type(4)));

#define BB 8
#define KK 1024
#define LL 1024
#define DD 1024
#define OO 6
#define EE 128
#define NN 768   // OO*EE

// ---------------------------------------------------------------------------
__device__ __forceinline__ void async_copy16(const void* gptr, void* lds) {
    __builtin_amdgcn_global_load_lds(
        (__attribute__((address_space(1))) void*)gptr,
        (__attribute__((address_space(3))) void*)lds,
        16, 0, 0);
}

__device__ __forceinline__ void split_bf16(float x, bf16_t& hi, bf16_t& lo) {
    hi = (bf16_t)x;
    lo = (bf16_t)(x - (float)hi);
}

// squash helper: sp[12] (slot s = element s*64+lane of a 768-row), -> vv[12].
__device__ __forceinline__ void squash_regs(const float* sp, float* vv, int lane) {
#pragma unroll
    for (int o = 0; o < 6; ++o) {
        float t = sp[2*o]*sp[2*o] + sp[2*o+1]*sp[2*o+1];
#pragma unroll
        for (int off = 32; off > 0; off >>= 1) t += __shfl_xor(t, off, 64);
        const float sc = t / (1.0f + t) / (sqrtf(t) + 1e-8f);
        vv[2*o]   = sc * sp[2*o];
        vv[2*o+1] = sc * sp[2*o+1];
    }
}

// ---------------------------------------------------------------------------
// Fused prep: [0,8192) convert A; [8192,8960) transpose+convert W;
// [8960,8969) zero sbuf (3*8*768 floats).
__global__ __launch_bounds__(256) void prep_kernel(
    const float* __restrict__ A, bf16_t* __restrict__ Ah, bf16_t* __restrict__ Al,
    const float* __restrict__ W, bf16_t* __restrict__ Wth, bf16_t* __restrict__ Wtl,
    float* __restrict__ sbuf)
{
    const int bx = blockIdx.x;
    if (bx < 8192) {
        const long i = ((long)bx * 256 + threadIdx.x) * 4;
        const float4 x = *(const float4*)(A + i);
        union { bf16_t h[4]; uint2 u; } ph, pl;
        split_bf16(x.x, ph.h[0], pl.h[0]);
        split_bf16(x.y, ph.h[1], pl.h[1]);
        split_bf16(x.z, ph.h[2], pl.h[2]);
        split_bf16(x.w, ph.h[3], pl.h[3]);
        *(uint2*)(Ah + i) = ph.u;
        *(uint2*)(Al + i) = pl.u;
    } else if (bx < 8960) {
        __shared__ float t[32][33];
        const int flat = bx - 8192;          // 0..767
        const int o  = flat / 128;
        const int rem = flat % 128;
        const int d0 = (rem & 31) * 32;
        const int e0 = (rem >> 5) * 32;
        const int tx = threadIdx.x & 31;
        const int ty = threadIdx.x >> 5;
        const float* Wo = W + (long)o * DD * EE;
        bf16_t* Ho = Wth + (long)o * EE * DD;
        bf16_t* Lo = Wtl + (long)o * EE * DD;
#pragma unroll
        for (int p = 0; p < 4; ++p)
            t[p * 8 + ty][tx] = Wo[(long)(d0 + p * 8 + ty) * EE + e0 + tx];
        __syncthreads();
#pragma unroll
        for (int p = 0; p < 4; ++p) {
            const float val = t[tx][p * 8 + ty];
            bf16_t h, l;
            split_bf16(val, h, l);
            const long idx = (long)(e0 + p * 8 + ty) * DD + d0 + tx;
            Ho[idx] = h;
            Lo[idx] = l;
        }
    } else {
        const int i = (bx - 8960) * 1024 + threadIdx.x;   // 9*1024 >= 9216... 
#pragma unroll
        for (int r = 0; r < 4; ++r) {
            const int idx = (bx - 8960) * 1024 + r * 256 + threadIdx.x;
            if (idx < 3 * BB * NN) sbuf[idx] = 0.f;
        }
        (void)i;
    }
}

// ---------------------------------------------------------------------------
// priors GEMM (3-term bf16 split) + fused iter-0 s epilogue.
// 128x64 tile, BK=32. 1-D grid 768 with XCD-aware swizzle: per XCD, bn is the
// fast dim so ~12 co-resident blocks share one A-tile (512 KB) + B (3 MB) in
// that XCD's 4 MB L2 — A is fetched from HBM once, not 12x.
__global__ __launch_bounds__(256) void gemm_priors(
    const bf16_t* __restrict__ Ah, const bf16_t* __restrict__ Al,
    const bf16_t* __restrict__ Bh, const bf16_t* __restrict__ Bl,
    float* __restrict__ C, float* __restrict__ s0)
{
    __shared__ alignas(16) bf16_t sAh[128 * 32];
    __shared__ alignas(16) bf16_t sAl[128 * 32];
    __shared__ alignas(16) bf16_t sBh[64 * 32];
    __shared__ alignas(16) bf16_t sBl[64 * 32];
    __shared__ float sRed[64];

    const int bid  = blockIdx.x;
    const int xcd  = bid & 7;
    const int s    = bid >> 3;        // 0..95
    const int bn   = s % 12;
    const int bm   = (s / 12) * 8 + xcd;   // 0..63

    const int tid  = threadIdx.x;
    const int w    = tid >> 6;
    const int lane = tid & 63;
    const int qr   = (w >> 1) * 64;
    const int qc   = (w & 1) * 32;
    const int r16  = lane & 15;
    const int q    = lane >> 4;

    f32x4 acc[4][2] = {};

    const int mrowA = w * 32 + (lane >> 2);
    const int mrowB = w * 16 + (lane >> 2);
    const int kcol  = (lane & 3) * 8;

    const long aoff = (long)(bm * 128 + mrowA) * DD + kcol;
    const long boff = (long)(bn * 64  + mrowB) * DD + kcol;
    const bf16_t* gAh0 = Ah + aoff;  const bf16_t* gAh1 = gAh0 + 16 * DD;
    const bf16_t* gAl0 = Al + aoff;  const bf16_t* gAl1 = gAl0 + 16 * DD;
    const bf16_t* gBh  = Bh + boff;
    const bf16_t* gBl  = Bl + boff;

    bf16_t* lAh0 = sAh + (w * 2 + 0) * 512;
    bf16_t* lAh1 = sAh + (w * 2 + 1) * 512;
    bf16_t* lAl0 = sAl + (w * 2 + 0) * 512;
    bf16_t* lAl1 = sAl + (w * 2 + 1) * 512;
    bf16_t* lBh  = sBh + w * 512;
    bf16_t* lBl  = sBl + w * 512;

    for (int kt = 0; kt < DD / 32; ++kt) {
        const int k0 = kt * 32;
        async_copy16(gAh0 + k0, lAh0);
        async_copy16(gAh1 + k0, lAh1);
        async_copy16(gAl0 + k0, lAl0);
        async_copy16(gAl1 + k0, lAl1);
        async_copy16(gBh  + k0, lBh);
        async_copy16(gBl  + k0, lBl);
        __syncthreads();

        bf16x8 ah[4], al[4], bh[2], bl[2];
#pragma unroll
        for (int i = 0; i < 4; ++i) {
            const int ra = (qr + 16 * i + r16) * 32 + q * 8;
            ah[i] = *(const bf16x8*)(sAh + ra);
            al[i] = *(const bf16x8*)(sAl + ra);
        }
#pragma unroll
        for (int j = 0; j < 2; ++j) {
            const int rb = (qc + 16 * j + r16) * 32 + q * 8;
            bh[j] = *(const bf16x8*)(sBh + rb);
            bl[j] = *(const bf16x8*)(sBl + rb);
        }
#pragma unroll
        for (int i = 0; i < 4; ++i)
#pragma unroll
            for (int j = 0; j < 2; ++j) {
                acc[i][j] = __builtin_amdgcn_mfma_f32_16x16x32_bf16(
                    al[i], bh[j], acc[i][j], 0, 0, 0);
                acc[i][j] = __builtin_amdgcn_mfma_f32_16x16x32_bf16(
                    ah[i], bl[j], acc[i][j], 0, 0, 0);
                acc[i][j] = __builtin_amdgcn_mfma_f32_16x16x32_bf16(
                    ah[i], bh[j], acc[i][j], 0, 0, 0);
            }
        __syncthreads();
    }

    // C store. C/D layout: col = lane&15, row = (lane>>4)*4 + reg.
#pragma unroll
    for (int i = 0; i < 4; ++i)
#pragma unroll
        for (int j = 0; j < 2; ++j) {
            const int col = bn * 64 + qc + 16 * j + r16;
#pragma unroll
            for (int r = 0; r < 4; ++r) {
                const int row = bm * 128 + qr + 16 * i + q * 4 + r;
                C[(long)row * NN + col] = acc[i][j][r];
            }
        }

    // iter-0 s epilogue: column sums of this block's 128 rows (b = bm>>3).
    if (tid < 64) sRed[tid] = 0.f;
    __syncthreads();
#pragma unroll
    for (int j = 0; j < 2; ++j) {
        float cs = 0.f;
#pragma unroll
        for (int i = 0; i < 4; ++i)
            cs += acc[i][j][0] + acc[i][j][1] + acc[i][j][2] + acc[i][j][3];
        cs += __shfl_xor(cs, 16, 64);
        cs += __shfl_xor(cs, 32, 64);
        if (lane < 16)
            atomicAdd(&sRed[qc + 16 * j + r16], cs);
    }
    __syncthreads();
    if (tid < 64)
        atomicAdd(&s0[(bm >> 3) * NN + bn * 64 + tid], sRed[tid] * (1.0f / 6.0f));
}

// ---------------------------------------------------------------------------
// Fused routing step: v = squash(s_prev); per (b,k): delta = priors.v;
// g' = (first ? delta : g+delta); probs = mask ? 1/6 : softmax(g');
// s_cur += probs * priors. grid 1024: b = blk>>7, 8 k/block, 4 waves x 2 rows.
__global__ __launch_bounds__(256) void pgs_kernel(
    const float* __restrict__ priors, const float* __restrict__ s_prev,
    const int* __restrict__ mask, float* __restrict__ g,
    float* __restrict__ probs, float* __restrict__ s_cur, int first)
{
    const int blk  = blockIdx.x;
    const int b    = blk >> 7;
    const int k8   = (blk & 127) * 8;
    const int w    = threadIdx.x >> 6;
    const int lane = threadIdx.x & 63;

    float vv[12];
    {
        float sp[12];
#pragma unroll
        for (int s = 0; s < 12; ++s) sp[s] = s_prev[b * NN + s * 64 + lane];
        squash_regs(sp, vv, lane);
    }

    float sacc[12];
#pragma unroll
    for (int s = 0; s < 12; ++s) sacc[s] = 0.f;

#pragma unroll
    for (int r = 0; r < 2; ++r) {
        const int k = k8 + w * 2 + r;
        const long rid = (long)b * KK + k;
        const float* pr = priors + rid * NN;
        float pp[12];
#pragma unroll
        for (int s = 0; s < 12; ++s) pp[s] = pr[s * 64 + lane];

        float d[6];
#pragma unroll
        for (int o = 0; o < 6; ++o) {
            float t = pp[2*o] * vv[2*o] + pp[2*o+1] * vv[2*o+1];
#pragma unroll
            for (int off = 32; off > 0; off >>= 1) t += __shfl_xor(t, off, 64);
            d[o] = t;
        }

        if (first) {
            if (lane < 6) {
                float x = d[0];
#pragma unroll
                for (int o = 1; o < 6; ++o) if (lane == o) x = d[o];
                g[rid * 6 + lane] = x;
            }
        } else {
#pragma unroll
            for (int o = 0; o < 6; ++o) d[o] += g[rid * 6 + o];
        }

        float p[6];
        if (mask[rid] != 0) {
#pragma unroll
            for (int o = 0; o < 6; ++o) p[o] = 1.0f / 6.0f;
        } else {
            float m = d[0];
#pragma unroll
            for (int o = 1; o < 6; ++o) m = fmaxf(m, d[o]);
            float ssum = 0.f;
#pragma unroll
            for (int o = 0; o < 6; ++o) { p[o] = expf(d[o] - m); ssum += p[o]; }
            const float inv = 1.0f / ssum;
#pragma unroll
            for (int o = 0; o < 6; ++o) p[o] *= inv;
        }

        if (!first && lane < 6) {
            float x = p[0];
#pragma unroll
            for (int o = 1; o < 6; ++o) if (lane == o) x = p[o];
            probs[rid * 6 + lane] = x;
        }

#pragma unroll
        for (int s = 0; s < 12; ++s) sacc[s] = fmaf(p[s >> 1], pp[s], sacc[s]);
    }

    __shared__ float red[4][768];
#pragma unroll
    for (int s = 0; s < 12; ++s) red[w][s * 64 + lane] = sacc[s];
    __syncthreads();
    const int t = threadIdx.x;
#pragma unroll
    for (int i = 0; i < 3; ++i) {
        const int flat = t + i * 256;
        atomicAdd(&s_cur[b * NN + flat],
                  red[0][flat] + red[1][flat] + red[2][flat] + red[3][flat]);
    }
}

// ---------------------------------------------------------------------------
// Output: V-section (squash(s2) broadcast over L) + P-section (probs bcast).
__global__ __launch_bounds__(256) void bcast_kernel(
    const float* __restrict__ s2, const float* __restrict__ P,
    float* __restrict__ out)
{
    const int blk = blockIdx.x;
    if (blk < 2048) {
        const int b  = blk >> 8;
        const int l0 = (blk & 255) * 4;
        const int w = threadIdx.x >> 6, lane = threadIdx.x & 63;
        __shared__ float vrow[768];
        if (w == 0) {
            float sp[12], vv[12];
#pragma unroll
            for (int s = 0; s < 12; ++s) sp[s] = s2[b * NN + s * 64 + lane];
            squash_regs(sp, vv, lane);
#pragma unroll
            for (int s = 0; s < 12; ++s) vrow[s * 64 + lane] = vv[s];
        }
        __syncthreads();
        float* dst = out + ((long)b * LL + l0) * NN;
        const int t = threadIdx.x;
#pragma unroll
        for (int i = 0; i < 3; ++i) {
            const int idx = t * 12 + i * 4;
            *(float4*)(dst + idx) = *(const float4*)(vrow + (idx % NN));
        }
    } else {
        const long NVF = (long)BB * LL * OO * EE;
        const int blk2 = blk - 2048;
        const long base = (long)blk2 * 4096;
        const int b = (int)(base / ((long)LL * KK * OO));
        const int choff = (int)(base % (KK * OO));
        const float* src = P + (long)b * (KK * OO);
        float* dst = out + NVF + base;
        const int t = threadIdx.x;
#pragma unroll
        for (int i = 0; i < 4; ++i) {
            int off = choff + t * 16 + i * 4;
            if (off >= KK * OO) off -= KK * OO;
            *(float4*)(dst + t * 16 + i * 4) = *(const float4*)(src + off);
        }
    }
}

// ---------------------------------------------------------------------------
extern "C" void kernel_launch(void* const* d_in, const int* in_sizes, int n_in,
                              void* d_out, int out_size, void* d_ws, size_t ws_size,
                              hipStream_t stream)
{
    (void)in_sizes; (void)n_in; (void)out_size; (void)ws_size;
    const float* u    = (const float*)d_in[0];
    const float* W    = (const float*)d_in[2];
    const int*   mask = (const int*)d_in[3];
    float*       out  = (float*)d_out;

    char* ws = (char*)d_ws;
    size_t off = 0;
    float*  priors = (float*)(ws + off);  off += (size_t)8192 * NN * 4;
    bf16_t* Ah     = (bf16_t*)(ws + off); off += (size_t)8192 * DD * 2;
    bf16_t* Al     = (bf16_t*)(ws + off); off += (size_t)8192 * DD * 2;
    bf16_t* Wth    = (bf16_t*)(ws + off); off += (size_t)OO * EE * DD * 2;
    bf16_t* Wtl    = (bf16_t*)(ws + off); off += (size_t)OO * EE * DD * 2;
    float*  g      = (float*)(ws + off);  off += (size_t)BB * KK * OO * 4;
    float*  probs  = (float*)(ws + off);  off += (size_t)BB * KK * OO * 4;
    float*  sbuf   = (float*)(ws + off);  off += (size_t)3 * BB * NN * 4;
    float*  s0 = sbuf, *s1 = sbuf + BB * NN, *s2 = sbuf + 2 * BB * NN;

    hipLaunchKernelGGL(prep_kernel, dim3(8969), dim3(256), 0, stream,
                       u, Ah, Al, W, Wth, Wtl, sbuf);
    hipLaunchKernelGGL(gemm_priors, dim3(768), dim3(256), 0, stream,
                       Ah, Al, Wth, Wtl, priors, s0);
    hipLaunchKernelGGL(pgs_kernel, dim3(1024), dim3(256), 0, stream,
                       priors, s0, mask, g, probs, s1, 1);
    hipLaunchKernelGGL(pgs_kernel, dim3(1024), dim3(256), 0, stream,
                       priors, s1, mask, g, probs, s2, 0);
    hipLaunchKernelGGL(bcast_kernel, dim3(14336), dim3(256), 0, stream,
                       s2, probs, out);
}

// Round 6
// 367.997 us; speedup vs baseline: 1.0224x; 1.0156x over previous
//
#include <hip/hip_runtime.h>
#include <hip/hip_bf16.h>
#include <stdint.h>

typedef __bf16 bf16_t;
typedef __bf16 bf16x8 __attribute__((ext_vector_type(8)));
typedef float f32x16 __attribute__((ext_vector_type(16)));

#define BB 8
#define KK 1024
#define LL 1024
#define DD 1024
#define OO 6
#define EE 128
#define NN 768   // OO*EE

// ---------------------------------------------------------------------------
__device__ __forceinline__ void async_copy16(const void* gptr, void* lds) {
    __builtin_amdgcn_global_load_lds(
        (__attribute__((address_space(1))) void*)gptr,
        (__attribute__((address_space(3))) void*)lds,
        16, 0, 0);
}

__device__ __forceinline__ void split_bf16(float x, bf16_t& hi, bf16_t& lo) {
    hi = (bf16_t)x;
    lo = (bf16_t)(x - (float)hi);
}

// squash helper: sp[12] (slot s = element s*64+lane of a 768-row) -> vv[12].
__device__ __forceinline__ void squash_regs(const float* sp, float* vv, int lane) {
#pragma unroll
    for (int o = 0; o < 6; ++o) {
        float t = sp[2*o]*sp[2*o] + sp[2*o+1]*sp[2*o+1];
#pragma unroll
        for (int off = 32; off > 0; off >>= 1) t += __shfl_xor(t, off, 64);
        const float sc = t / (1.0f + t) / (sqrtf(t) + 1e-8f);
        vv[2*o]   = sc * sp[2*o];
        vv[2*o+1] = sc * sp[2*o+1];
    }
}

// ---------------------------------------------------------------------------
// Fused prep: [0,8192) convert A; [8192,8960) transpose+convert W;
// [8960,8969) zero sbuf (3*8*768 floats).
__global__ __launch_bounds__(256) void prep_kernel(
    const float* __restrict__ A, bf16_t* __restrict__ Ah, bf16_t* __restrict__ Al,
    const float* __restrict__ W, bf16_t* __restrict__ Wth, bf16_t* __restrict__ Wtl,
    float* __restrict__ sbuf)
{
    const int bx = blockIdx.x;
    if (bx < 8192) {
        const long i = ((long)bx * 256 + threadIdx.x) * 4;
        const float4 x = *(const float4*)(A + i);
        union { bf16_t h[4]; uint2 u; } ph, pl;
        split_bf16(x.x, ph.h[0], pl.h[0]);
        split_bf16(x.y, ph.h[1], pl.h[1]);
        split_bf16(x.z, ph.h[2], pl.h[2]);
        split_bf16(x.w, ph.h[3], pl.h[3]);
        *(uint2*)(Ah + i) = ph.u;
        *(uint2*)(Al + i) = pl.u;
    } else if (bx < 8960) {
        __shared__ float t[32][33];
        const int flat = bx - 8192;          // 0..767
        const int o  = flat / 128;
        const int rem = flat % 128;
        const int d0 = (rem & 31) * 32;
        const int e0 = (rem >> 5) * 32;
        const int tx = threadIdx.x & 31;
        const int ty = threadIdx.x >> 5;
        const float* Wo = W + (long)o * DD * EE;
        bf16_t* Ho = Wth + (long)o * EE * DD;
        bf16_t* Lo = Wtl + (long)o * EE * DD;
#pragma unroll
        for (int p = 0; p < 4; ++p)
            t[p * 8 + ty][tx] = Wo[(long)(d0 + p * 8 + ty) * EE + e0 + tx];
        __syncthreads();
#pragma unroll
        for (int p = 0; p < 4; ++p) {
            const float val = t[tx][p * 8 + ty];
            bf16_t h, l;
            split_bf16(val, h, l);
            const long idx = (long)(e0 + p * 8 + ty) * DD + d0 + tx;
            Ho[idx] = h;
            Lo[idx] = l;
        }
    } else {
#pragma unroll
        for (int r = 0; r < 4; ++r) {
            const int idx = (bx - 8960) * 1024 + r * 256 + threadIdx.x;
            if (idx < 3 * BB * NN) sbuf[idx] = 0.f;
        }
    }
}

// ---------------------------------------------------------------------------
// priors GEMM (3-term bf16 split) using mfma_f32_32x32x16_bf16.
// 128x64 tile, BK=32, 1-D grid 768 XCD-swizzled (bn fast within an XCD so one
// A-tile is L2-resident per XCD). Each wave: 64 rows x 32 cols = two 32x32
// C-tiles, 2 k-halves per BK step, 3 split terms -> 12 mfma / 6 ds_read_b128.
__global__ __launch_bounds__(256) void gemm_priors(
    const bf16_t* __restrict__ Ah, const bf16_t* __restrict__ Al,
    const bf16_t* __restrict__ Bh, const bf16_t* __restrict__ Bl,
    float* __restrict__ C, float* __restrict__ s0)
{
    __shared__ alignas(16) bf16_t sAh[128 * 32];
    __shared__ alignas(16) bf16_t sAl[128 * 32];
    __shared__ alignas(16) bf16_t sBh[64 * 32];
    __shared__ alignas(16) bf16_t sBl[64 * 32];
    __shared__ float sRed[64];

    const int bid  = blockIdx.x;
    const int xcd  = bid & 7;
    const int sgp  = bid >> 3;              // 0..95
    const int bn   = sgp % 12;
    const int bm   = (sgp / 12) * 8 + xcd;  // 0..63

    const int tid  = threadIdx.x;
    const int w    = tid >> 6;
    const int lane = tid & 63;
    const int qr   = (w >> 1) * 64;
    const int qc   = (w & 1) * 32;
    const int l31  = lane & 31;
    const int lh   = lane >> 5;             // 0/1

    f32x16 acc[2] = {};

    // staging map (unchanged layout): row-major [row][32 k-elems]
    const int mrowA = w * 32 + (lane >> 2);
    const int mrowB = w * 16 + (lane >> 2);
    const int kcol  = (lane & 3) * 8;

    const long aoff = (long)(bm * 128 + mrowA) * DD + kcol;
    const long boff = (long)(bn * 64  + mrowB) * DD + kcol;
    const bf16_t* gAh0 = Ah + aoff;  const bf16_t* gAh1 = gAh0 + 16 * DD;
    const bf16_t* gAl0 = Al + aoff;  const bf16_t* gAl1 = gAl0 + 16 * DD;
    const bf16_t* gBh  = Bh + boff;
    const bf16_t* gBl  = Bl + boff;

    bf16_t* lAh0 = sAh + (w * 2 + 0) * 512;
    bf16_t* lAh1 = sAh + (w * 2 + 1) * 512;
    bf16_t* lAl0 = sAl + (w * 2 + 0) * 512;
    bf16_t* lAl1 = sAl + (w * 2 + 1) * 512;
    bf16_t* lBh  = sBh + w * 512;
    bf16_t* lBl  = sBl + w * 512;

    for (int kt = 0; kt < DD / 32; ++kt) {
        const int k0 = kt * 32;
        async_copy16(gAh0 + k0, lAh0);
        async_copy16(gAh1 + k0, lAh1);
        async_copy16(gAl0 + k0, lAl0);
        async_copy16(gAl1 + k0, lAl1);
        async_copy16(gBh  + k0, lBh);
        async_copy16(gBl  + k0, lBl);
        __syncthreads();

#pragma unroll
        for (int kh = 0; kh < 2; ++kh) {
            const int kb = kh * 16 + lh * 8;   // elem offset within BK row
            bf16x8 ahf[2], alf[2], bhf, blf;
#pragma unroll
            for (int i = 0; i < 2; ++i) {
                const int ra = (qr + i * 32 + l31) * 32 + kb;
                ahf[i] = *(const bf16x8*)(sAh + ra);
                alf[i] = *(const bf16x8*)(sAl + ra);
            }
            const int rb = (qc + l31) * 32 + kb;
            bhf = *(const bf16x8*)(sBh + rb);
            blf = *(const bf16x8*)(sBl + rb);
#pragma unroll
            for (int i = 0; i < 2; ++i) {
                acc[i] = __builtin_amdgcn_mfma_f32_32x32x16_bf16(
                    alf[i], bhf, acc[i], 0, 0, 0);
                acc[i] = __builtin_amdgcn_mfma_f32_32x32x16_bf16(
                    ahf[i], blf, acc[i], 0, 0, 0);
                acc[i] = __builtin_amdgcn_mfma_f32_32x32x16_bf16(
                    ahf[i], bhf, acc[i], 0, 0, 0);
            }
        }
        __syncthreads();
    }

    // C store. 32x32 C/D layout: col = lane&31, row = (r&3)+8*(r>>2)+4*(lane>>5)
    const int col = bn * 64 + qc + l31;
#pragma unroll
    for (int i = 0; i < 2; ++i) {
#pragma unroll
        for (int r = 0; r < 16; ++r) {
            const int row = bm * 128 + qr + i * 32 + (r & 3) + 8 * (r >> 2) + 4 * lh;
            C[(long)row * NN + col] = acc[i][r];
        }
    }

    // iter-0 s epilogue: column sums over this block's 128 rows (b = bm>>3).
    if (tid < 64) sRed[tid] = 0.f;
    __syncthreads();
    float cs = 0.f;
#pragma unroll
    for (int i = 0; i < 2; ++i)
#pragma unroll
        for (int r = 0; r < 16; ++r) cs += acc[i][r];
    cs += __shfl_xor(cs, 32, 64);
    if (lane < 32) atomicAdd(&sRed[qc + l31], cs);
    __syncthreads();
    if (tid < 64)
        atomicAdd(&s0[(bm >> 3) * NN + bn * 64 + tid], sRed[tid] * (1.0f / 6.0f));
}

// ---------------------------------------------------------------------------
// Fused routing step: v = squash(s_prev); per (b,k): delta = priors.v;
// g' = (first ? delta : g+delta); p = mask ? 1/6 : softmax(g');
// s_cur += p * priors. If outP != null (last iter): broadcast p over L into
// the output's P-section directly. grid 1024: b=blk>>7, 8 k/block.
__global__ __launch_bounds__(256) void pgs_kernel(
    const float* __restrict__ priors, const float* __restrict__ s_prev,
    const int* __restrict__ mask, float* __restrict__ g,
    float* __restrict__ s_cur, float* __restrict__ outP, int first)
{
    const int blk  = blockIdx.x;
    const int b    = blk >> 7;
    const int k8   = (blk & 127) * 8;
    const int w    = threadIdx.x >> 6;
    const int lane = threadIdx.x & 63;

    __shared__ float red[4][768];
    __shared__ float pstage[48];

    float vv[12];
    {
        float sp[12];
#pragma unroll
        for (int s = 0; s < 12; ++s) sp[s] = s_prev[b * NN + s * 64 + lane];
        squash_regs(sp, vv, lane);
    }

    float sacc[12];
#pragma unroll
    for (int s = 0; s < 12; ++s) sacc[s] = 0.f;

#pragma unroll
    for (int r = 0; r < 2; ++r) {
        const int k = k8 + w * 2 + r;
        const long rid = (long)b * KK + k;
        const float* pr = priors + rid * NN;
        float pp[12];
#pragma unroll
        for (int s = 0; s < 12; ++s) pp[s] = pr[s * 64 + lane];

        float d[6];
#pragma unroll
        for (int o = 0; o < 6; ++o) {
            float t = pp[2*o] * vv[2*o] + pp[2*o+1] * vv[2*o+1];
#pragma unroll
            for (int off = 32; off > 0; off >>= 1) t += __shfl_xor(t, off, 64);
            d[o] = t;
        }

        if (first) {
            if (lane < 6) {
                float x = d[0];
#pragma unroll
                for (int o = 1; o < 6; ++o) if (lane == o) x = d[o];
                g[rid * 6 + lane] = x;
            }
        } else {
#pragma unroll
            for (int o = 0; o < 6; ++o) d[o] += g[rid * 6 + o];
        }

        float p[6];
        if (mask[rid] != 0) {
#pragma unroll
            for (int o = 0; o < 6; ++o) p[o] = 1.0f / 6.0f;
        } else {
            float m = d[0];
#pragma unroll
            for (int o = 1; o < 6; ++o) m = fmaxf(m, d[o]);
            float ssum = 0.f;
#pragma unroll
            for (int o = 0; o < 6; ++o) { p[o] = expf(d[o] - m); ssum += p[o]; }
            const float inv = 1.0f / ssum;
#pragma unroll
            for (int o = 0; o < 6; ++o) p[o] *= inv;
        }

        if (outP && lane < 6) {
            float x = p[0];
#pragma unroll
            for (int o = 1; o < 6; ++o) if (lane == o) x = p[o];
            pstage[(w * 2 + r) * 6 + lane] = x;
        }

#pragma unroll
        for (int s = 0; s < 12; ++s) sacc[s] = fmaf(p[s >> 1], pp[s], sacc[s]);
    }

#pragma unroll
    for (int s = 0; s < 12; ++s) red[w][s * 64 + lane] = sacc[s];
    __syncthreads();
    const int t = threadIdx.x;
#pragma unroll
    for (int i = 0; i < 3; ++i) {
        const int flat = t + i * 256;
        atomicAdd(&s_cur[b * NN + flat],
                  red[0][flat] + red[1][flat] + red[2][flat] + red[3][flat]);
    }

    if (outP) {
        // broadcast this block's 48 probs (8 k x 6 o) to all 1024 l positions.
        // out[b][l][k][o] flat = b*6291456 + l*6144 + k8*6 + ...
        float* base = outP + (long)b * (LL * KK * OO) + k8 * 6;
        const int j = t & 3;                 // float4 group: floats j*12..j*12+11
        const int lsub = t >> 2;             // 0..63
        const float4 c0 = *(const float4*)(pstage + j * 12);
        const float4 c1 = *(const float4*)(pstage + j * 12 + 4);
        const float4 c2 = *(const float4*)(pstage + j * 12 + 8);
#pragma unroll
        for (int lg = 0; lg < 16; ++lg) {
            float* dst = base + (long)(lg * 64 + lsub) * (KK * OO) + j * 12;
            *(float4*)(dst)     = c0;
            *(float4*)(dst + 4) = c1;
            *(float4*)(dst + 8) = c2;
        }
    }
}

// ---------------------------------------------------------------------------
// Output V-section: squash(s2) broadcast over L. grid 2048.
__global__ __launch_bounds__(256) void bcast_v_kernel(
    const float* __restrict__ s2, float* __restrict__ out)
{
    const int blk = blockIdx.x;
    const int b  = blk >> 8;
    const int l0 = (blk & 255) * 4;
    const int w = threadIdx.x >> 6, lane = threadIdx.x & 63;
    __shared__ float vrow[768];
    if (w == 0) {
        float sp[12], vvv[12];
#pragma unroll
        for (int s = 0; s < 12; ++s) sp[s] = s2[b * NN + s * 64 + lane];
        squash_regs(sp, vvv, lane);
#pragma unroll
        for (int s = 0; s < 12; ++s) vrow[s * 64 + lane] = vvv[s];
    }
    __syncthreads();
    float* dst = out + ((long)b * LL + l0) * NN;
    const int t = threadIdx.x;
#pragma unroll
    for (int i = 0; i < 3; ++i) {
        const int idx = t * 12 + i * 4;
        *(float4*)(dst + idx) = *(const float4*)(vrow + (idx % NN));
    }
}

// ---------------------------------------------------------------------------
extern "C" void kernel_launch(void* const* d_in, const int* in_sizes, int n_in,
                              void* d_out, int out_size, void* d_ws, size_t ws_size,
                              hipStream_t stream)
{
    (void)in_sizes; (void)n_in; (void)out_size; (void)ws_size;
    const float* u    = (const float*)d_in[0];
    const float* W    = (const float*)d_in[2];
    const int*   mask = (const int*)d_in[3];
    float*       out  = (float*)d_out;

    char* ws = (char*)d_ws;
    size_t off = 0;
    float*  priors = (float*)(ws + off);  off += (size_t)8192 * NN * 4;
    bf16_t* Ah     = (bf16_t*)(ws + off); off += (size_t)8192 * DD * 2;
    bf16_t* Al     = (bf16_t*)(ws + off); off += (size_t)8192 * DD * 2;
    bf16_t* Wth    = (bf16_t*)(ws + off); off += (size_t)OO * EE * DD * 2;
    bf16_t* Wtl    = (bf16_t*)(ws + off); off += (size_t)OO * EE * DD * 2;
    float*  g      = (float*)(ws + off);  off += (size_t)BB * KK * OO * 4;
    float*  sbuf   = (float*)(ws + off);  off += (size_t)3 * BB * NN * 4;
    float*  s0 = sbuf, *s1 = sbuf + BB * NN, *s2 = sbuf + 2 * BB * NN;

    const long NVF = (long)BB * LL * OO * EE;   // V-section size = 6,291,456

    hipLaunchKernelGGL(prep_kernel, dim3(8969), dim3(256), 0, stream,
                       u, Ah, Al, W, Wth, Wtl, sbuf);
    hipLaunchKernelGGL(gemm_priors, dim3(768), dim3(256), 0, stream,
                       Ah, Al, Wth, Wtl, priors, s0);
    hipLaunchKernelGGL(pgs_kernel, dim3(1024), dim3(256), 0, stream,
                       priors, s0, mask, g, s1, (float*)nullptr, 1);
    hipLaunchKernelGGL(pgs_kernel, dim3(1024), dim3(256), 0, stream,
                       priors, s1, mask, g, s2, out + NVF, 0);
    hipLaunchKernelGGL(bcast_v_kernel, dim3(2048), dim3(256), 0, stream,
                       s2, out);
}